// Round 4
// baseline (765.748 us; speedup 1.0000x reference)
//
#include <hip/hip_runtime.h>

#define AS1 __attribute__((address_space(1)))
#define AS3 __attribute__((address_space(3)))

typedef __bf16 bf16;
typedef __bf16 bf16x8 __attribute__((ext_vector_type(8)));
typedef __bf16 bf16x4v __attribute__((ext_vector_type(4)));
typedef float  f32x4  __attribute__((ext_vector_type(4)));
typedef float  f32x16 __attribute__((ext_vector_type(16)));

#define MFMA16(a,b,c) __builtin_amdgcn_mfma_f32_16x16x32_bf16((a),(b),(c),0,0,0)
#define MFMA32(a,b,c) __builtin_amdgcn_mfma_f32_32x32x16_bf16((a),(b),(c),0,0,0)
#define BARX() asm volatile("s_waitcnt lgkmcnt(0)\ns_barrier" ::: "memory")
#define VMW(n) asm volatile("s_waitcnt vmcnt(" #n ")" ::: "memory")

static __device__ __forceinline__ void gll16(const bf16* src, bf16* lds) {
  __builtin_amdgcn_global_load_lds((const AS1 void*)src, (AS3 void*)lds, 16, 0, 0);
}

// ---------------- Kernel 0: weights fp32 -> bf16 ----------------
__global__ void convw_k(const float* __restrict__ s, bf16* __restrict__ d) {
  int i = (blockIdx.x * 256 + threadIdx.x) * 4;
  float4 v = *(const float4*)(s + i);
  bf16x4v o;
  o[0] = (bf16)v.x; o[1] = (bf16)v.y; o[2] = (bf16)v.z; o[3] = (bf16)v.w;
  *(bf16x4v*)(d + i) = o;
}

// ------------- Kernel 1: transpose+convert feat [B,C,4096] -> [B,4096,C] bf16 -------------
__global__ void tconv_k(const float* __restrict__ f0, const float* __restrict__ f1,
                        bf16* __restrict__ xq, bf16* __restrict__ xkv) {
  const int z = blockIdx.z;
  const int b = z & 7;
  const float* src = (z < 8) ? f0 : f1;
  bf16* dst = (z < 8) ? xq : xkv;
  const int n0 = blockIdx.x * 32, c0 = blockIdx.y * 32;
  __shared__ float tile[32][33];
  const int tx = threadIdx.x, ty = threadIdx.y;
  const size_t base = (size_t)b * 512 * 4096;
#pragma unroll
  for (int i = 0; i < 4; i++) {
    int c = ty + i * 8;
    tile[c][tx] = src[base + (size_t)(c0 + c) * 4096 + n0 + tx];
  }
  __syncthreads();
  const size_t ob = (size_t)b * 4096 * 512;
#pragma unroll
  for (int i = 0; i < 4; i++) {
    int n = ty + i * 8;
    dst[ob + (size_t)(n0 + n) * 512 + c0 + tx] = (bf16)tile[tx][n];
  }
}

// ------------- Kernel 2: generic GEMM  out[r,co] = sum_k A[r,k]*W[co,k] + bias[co] -------------
// MODE 0: out bf16 [B,4096,512] plain                  (Q)
// MODE 3: out bf16 [B,4096,512], 16B-chunk c -> c^(row&7) within row  (K image)
// MODE 1: out bf16 tiled [B][128][co 512][kv 32], kv-chunk j -> j^((co>>1)&3)  (V image)
// MODE 2: out fp32 transposed [B,512,4096] + residual feat0  (final)
template<int MODE>
__global__ __launch_bounds__(256) void gemm_k(const bf16* __restrict__ A, const bf16* __restrict__ W,
                                              const float* __restrict__ bias, bf16* __restrict__ outB,
                                              float* __restrict__ outF, const float* __restrict__ resid) {
  const int b = blockIdx.y;
  const int rt = blockIdx.x >> 2, ct = blockIdx.x & 3;
  const int r0 = rt * 128, c0 = ct * 128;
  const int t = threadIdx.x, w = t >> 6, l = t & 63;
  __shared__ alignas(16) bf16 As[128 * 32];
  __shared__ alignas(16) bf16 Bs[128 * 32];
  f32x4 acc[4][4];
  const f32x4 fzero = {0.f, 0.f, 0.f, 0.f};
#pragma unroll
  for (int m = 0; m < 4; m++)
#pragma unroll
    for (int n = 0; n < 4; n++) acc[m][n] = fzero;
  const bf16* Ab = A + (size_t)b * 4096 * 512 + (size_t)r0 * 512;
  const int wr = (w >> 1) * 64, wc = (w & 1) * 64;
  for (int kk = 0; kk < 16; kk++) {
    const int k0 = kk * 32;
#pragma unroll
    for (int h = 0; h < 2; h++) {
      const int rowbase = w * 32 + h * 16;
      const int row = rowbase + (l >> 2);
      const int cl = (l & 3) ^ ((row >> 1) & 3);
      gll16(Ab + (size_t)row * 512 + k0 + cl * 8, As + rowbase * 32);
      gll16(W + (size_t)(c0 + row) * 512 + k0 + cl * 8, Bs + rowbase * 32);
    }
    __syncthreads();
    bf16x8 af[4], bfr[4];
#pragma unroll
    for (int m = 0; m < 4; m++) {
      const int row = wr + m * 16 + (l & 15);
      af[m] = *(const bf16x8*)(As + row * 32 + (((l >> 4) ^ ((row >> 1) & 3)) << 3));
    }
#pragma unroll
    for (int n = 0; n < 4; n++) {
      const int row = wc + n * 16 + (l & 15);
      bfr[n] = *(const bf16x8*)(Bs + row * 32 + (((l >> 4) ^ ((row >> 1) & 3)) << 3));
    }
#pragma unroll
    for (int m = 0; m < 4; m++)
#pragma unroll
      for (int n = 0; n < 4; n++)
        acc[m][n] = MFMA16(af[m], bfr[n], acc[m][n]);
    __syncthreads();
  }
#pragma unroll
  for (int n = 0; n < 4; n++) {
    const int co = c0 + wc + n * 16 + (l & 15);
    const float bv = bias[co];
#pragma unroll
    for (int m = 0; m < 4; m++) {
      const int rb = r0 + wr + m * 16 + ((l >> 4) << 2);
      if constexpr (MODE == 0) {
#pragma unroll
        for (int i = 0; i < 4; i++)
          outB[(size_t)b * 4096 * 512 + (size_t)(rb + i) * 512 + co] = (bf16)(acc[m][n][i] + bv);
      } else if constexpr (MODE == 3) {
#pragma unroll
        for (int i = 0; i < 4; i++) {
          const int row = rb + i;
          const int colp = (((co >> 3) ^ (row & 7)) << 3) | (co & 7);
          outB[(size_t)b * 4096 * 512 + (size_t)row * 512 + colp] = (bf16)(acc[m][n][i] + bv);
        }
      } else if constexpr (MODE == 1) {
        bf16x4v pk;
#pragma unroll
        for (int i = 0; i < 4; i++) pk[i] = (bf16)(acc[m][n][i] + bv);
        const int kvin = rb & 31;
        const int pos = ((kvin >> 3) ^ ((co >> 1) & 3));
        const size_t o = (((size_t)b * 128 + (rb >> 5)) * 512 + co) * 32 + (pos << 3) + (kvin & 7);
        *(bf16x4v*)(outB + o) = pk;
      } else {
        const size_t o = ((size_t)b * 512 + co) * 4096 + rb;
        float4 rv = *(const float4*)(resid + o);
        float4 ov;
        ov.x = acc[m][n][0] + bv + rv.x;
        ov.y = acc[m][n][1] + bv + rv.y;
        ov.z = acc[m][n][2] + bv + rv.z;
        ov.w = acc[m][n][3] + bv + rv.w;
        *(float4*)(outF + o) = ov;
      }
    }
  }
}

// ------------- Kernel 3: flash cross-attention, pair-split-C, 32x32x16 MFMA -------------
// 8 waves = 4 pairs; pair p owns q-rows [n0+32p, +32); wave half h owns C/co half h.
// Q [B,4096,512] plain; K image [B,4096,512] chunk^(key&7); V image [B][128][512 co][32 kv] chunk^((co>>1)&3)
__global__ __launch_bounds__(512, 2) void flash_k(const bf16* __restrict__ Q, const bf16* __restrict__ K,
                                                  const bf16* __restrict__ Vt, bf16* __restrict__ ctx) {
  __shared__ alignas(16) bf16 Ks[2][32 * 512];   // 64 KB dbuf
  __shared__ alignas(16) bf16 Vs[2][512 * 32];   // 64 KB dbuf
  __shared__ alignas(16) float Sx[8 * 1024];     // 32 KB exchange (4 pairs x 2 slots)
  const int flat = blockIdx.x;
  const int fs = (flat & 7) * 32 + (flat >> 3);  // XCD swizzle, bijective
  const int b = fs >> 5, n0 = (fs & 31) * 128;
  const int tid = threadIdx.x, w = tid >> 6, l = tid & 63;
  const int h = w & 1, p = w >> 1;
  const int h2 = l >> 5, q = l & 31;
  const int kmask = l & 7;

  // Q fragments (B-operand of QK): lane holds Q[n0+32p+q][h*256 + ki*16 + 8*h2 .. +7]
  bf16x8 qf[16];
  {
    const bf16* Qb = Q + ((size_t)b * 4096 + n0 + p * 32 + q) * 512 + h * 256 + h2 * 8;
#pragma unroll
    for (int ki = 0; ki < 16; ki++) qf[ki] = *(const bf16x8*)(Qb + ki * 16);
  }
  f32x16 acc[8];
#pragma unroll
  for (int cb = 0; cb < 8; cb++)
#pragma unroll
    for (int i = 0; i < 16; i++) acc[cb][i] = 0.f;
  f32x16 sp;   // my S partial for the previous tile (filled by QK each iter)
  float mrow = -1e30f, lrow = 0.f;

  const bf16* Kg = K + (size_t)b * 4096 * 512;
  const bf16* Vg = Vt + (size_t)b * 128 * 16384;
  asm volatile("s_waitcnt vmcnt(0)" ::: "memory");  // drain qf loads before counted staging

  // prologue: stage K(0) and V(0) into buf 0
#pragma unroll
  for (int j = 0; j < 4; j++) {
    const int row = w * 4 + j;
    gll16(Kg + row * 512 + l * 8, &Ks[0][0] + row * 512);
  }
#pragma unroll
  for (int j = 0; j < 4; j++) {
    const int r0v = w * 64 + j * 16;
    gll16(Vg + r0v * 32 + l * 8, &Vs[0][0] + r0v * 32);
  }

#pragma unroll 1
  for (int t = 0; t <= 128; ++t) {
    // ---- single wait point: completes K(t) and V(t-1); V(t+1)&K(t+1) stay in flight ----
    if (t == 0 || t == 128) { VMW(0); } else { VMW(4); }
    BARX();  // B1: all waves' K(t), V(t-1) now visible to everyone
    // ---- issue K(t+1) staging ----
    if (t <= 126) {
      const bf16* ks = Kg + (size_t)(t + 1) * 16384;
      bf16* kd = &Ks[(t + 1) & 1][0];
#pragma unroll
      for (int j = 0; j < 4; j++) {
        const int row = w * 4 + j;
        gll16(ks + row * 512 + l * 8, kd + row * 512);
      }
    }
    float* sl = &Sx[((p << 1) | (h ^ (t & 1))) << 10];
    // ---- softmax + PV for tile t-1 (uses sp from previous iter + partner's partial) ----
    if (t >= 1) {
      float4 pp[4];
#pragma unroll
      for (int k = 0; k < 4; k++)
        pp[k] = ((const float4*)sl)[(l << 2) + (k ^ (l & 3))];
      float e[16];
#pragma unroll
      for (int k = 0; k < 4; k++) {
        e[4 * k + 0] = sp[4 * k + 0] + pp[k].x;
        e[4 * k + 1] = sp[4 * k + 1] + pp[k].y;
        e[4 * k + 2] = sp[4 * k + 2] + pp[k].z;
        e[4 * k + 3] = sp[4 * k + 3] + pp[k].w;
      }
      float pmax = e[0];
#pragma unroll
      for (int i = 1; i < 16; i++) pmax = fmaxf(pmax, e[i]);
      pmax = fmaxf(pmax, __shfl_xor(pmax, 32));
      if (!__all(pmax <= mrow + 8.0f)) {
        const float mnew = fmaxf(mrow, pmax);
        const float scl = __expf(mrow - mnew);
        mrow = mnew;
        lrow *= scl;
        const int sclI = __float_as_int(scl);
        // per-acc-row scales: row of reg r=4a+i is qr = i + 8a + 4*h2 (owner lane qr)
        f32x4 s4[4];
#pragma unroll
        for (int a = 0; a < 4; a++)
#pragma unroll
          for (int i = 0; i < 4; i++)
            s4[a][i] = __int_as_float(
                __builtin_amdgcn_ds_bpermute((8 * a + 4 * h2 + i) << 2, sclI));
#pragma unroll
        for (int cb = 0; cb < 8; cb++)
#pragma unroll
          for (int a = 0; a < 4; a++)
#pragma unroll
            for (int i = 0; i < 4; i++) acc[cb][4 * a + i] *= s4[a][i];
      }
#pragma unroll
      for (int i = 0; i < 16; i++) e[i] = __expf(e[i] - mrow);
      float rs = 0.f;
#pragma unroll
      for (int i = 0; i < 16; i++) rs += e[i];
      rs += __shfl_xor(rs, 32);
      lrow += rs;
      // pack P -> bf16, build PV A-fragments via cross-half swap
      uint u[8], su[8];
#pragma unroll
      for (int k = 0; k < 8; k++) {
        asm("v_cvt_pk_bf16_f32 %0, %1, %2" : "=v"(u[k]) : "v"(e[2 * k]), "v"(e[2 * k + 1]));
        su[k] = (uint)__shfl_xor((int)u[k], 32);
      }
      union { uint i4[4]; bf16x8 v; } f0u, f1u;
      const bool lo = (h2 == 0);
      f0u.i4[0] = lo ? u[0] : su[2]; f0u.i4[1] = lo ? u[1] : su[3];
      f0u.i4[2] = lo ? su[0] : u[2]; f0u.i4[3] = lo ? su[1] : u[3];
      f1u.i4[0] = lo ? u[4] : su[6]; f1u.i4[1] = lo ? u[5] : su[7];
      f1u.i4[2] = lo ? su[4] : u[6]; f1u.i4[3] = lo ? su[5] : u[7];
      const bf16x8 pf0 = f0u.v, pf1 = f1u.v;
      const bf16* vb0 = &Vs[(t - 1) & 1][0];
#pragma unroll
      for (int cb = 0; cb < 8; cb++) {
        const int co = h * 256 + cb * 32 + q;
        const int cm = (co >> 1) & 3;
        const bf16* vr = vb0 + co * 32;
        bf16x8 v0 = *(const bf16x8*)(vr + (((h2) ^ cm) << 3));
        bf16x8 v1 = *(const bf16x8*)(vr + (((2 + h2) ^ cm) << 3));
        acc[cb] = MFMA32(pf0, v0, acc[cb]);
        acc[cb] = MFMA32(pf1, v1, acc[cb]);
      }
    }
    // ---- QK(t): S_partial[32 keys][32 q] over my C-half; write to exchange slot ----
    if (t <= 127) {
#pragma unroll
      for (int i = 0; i < 16; i++) sp[i] = 0.f;
      const bf16* kb = &Ks[t & 1][0] + (size_t)q * 512;
#pragma unroll
      for (int ki = 0; ki < 16; ki++) {
        const int c = h * 32 + ki * 2 + h2;
        bf16x8 af = *(const bf16x8*)(kb + ((c ^ kmask) << 3));
        sp = MFMA32(af, qf[ki], sp);
      }
#pragma unroll
      for (int k = 0; k < 4; k++) {
        float4 v = {sp[4 * k], sp[4 * k + 1], sp[4 * k + 2], sp[4 * k + 3]};
        ((float4*)sl)[(l << 2) + (k ^ (l & 3))] = v;
      }
    }
    BARX();  // B2: PV reads of V(t-1) done; S(t) writes visible next iter
    // ---- issue V(t+1) staging ----
    if (t <= 126) {
      const bf16* vs = Vg + (size_t)(t + 1) * 16384;
      bf16* vd = &Vs[(t + 1) & 1][0];
#pragma unroll
      for (int j = 0; j < 4; j++) {
        const int r0v = w * 64 + j * 16;
        gll16(vs + r0v * 32 + l * 8, vd + r0v * 32);
      }
    }
  }

  // ---- epilogue: per-row denominators via bpermute, scale, store ----
  const float inv = 0.04419417382415922f / lrow;
  const int invI = __float_as_int(inv);
  float fin[16];
#pragma unroll
  for (int r = 0; r < 16; r++) {
    const int qr = (r & 3) + 8 * (r >> 2) + 4 * h2;
    fin[r] = __int_as_float(__builtin_amdgcn_ds_bpermute(qr << 2, invI));
  }
  const size_t ob = (size_t)b * 4096 * 512;
#pragma unroll
  for (int cb = 0; cb < 8; cb++) {
    const int co = h * 256 + cb * 32 + q;
#pragma unroll
    for (int r = 0; r < 16; r++) {
      const int qr = (r & 3) + 8 * (r >> 2) + 4 * h2;
      ctx[ob + (size_t)(n0 + p * 32 + qr) * 512 + co] = (bf16)(acc[cb][r] * fin[r]);
    }
  }
}

extern "C" void kernel_launch(void* const* d_in, const int* in_sizes, int n_in,
                              void* d_out, int out_size, void* d_ws, size_t ws_size,
                              hipStream_t stream) {
  const float* feat0 = (const float*)d_in[0];
  const float* feat1 = (const float*)d_in[1];
  const float* Wq = (const float*)d_in[2];
  const float* bq = (const float*)d_in[3];
  const float* Wk = (const float*)d_in[4];
  const float* bk = (const float*)d_in[5];
  const float* Wv = (const float*)d_in[6];
  const float* bv = (const float*)d_in[7];
  const float* Wo = (const float*)d_in[8];
  const float* bo = (const float*)d_in[9];
  float* out = (float*)d_out;

  char* ws = (char*)d_ws;
  bf16* Wqb = (bf16*)(ws);
  bf16* Wkb = (bf16*)(ws + (1 << 19));
  bf16* Wvb = (bf16*)(ws + 2 * (size_t)(1 << 19));
  bf16* Wob = (bf16*)(ws + 3 * (size_t)(1 << 19));
  const size_t TEN = (size_t)8 * 4096 * 512 * 2;  // 33.55 MB per bf16 tensor
  char* p = ws + 4 * (size_t)(1 << 19);
  bf16* Xq  = (bf16*)(p);
  bf16* Xkv = (bf16*)(p + TEN);
  bf16* Qb  = (bf16*)(p + 2 * TEN);
  bf16* Kb  = (bf16*)(p + 3 * TEN);
  bf16* Vtb = (bf16*)(p + 4 * TEN);
  bf16* ctx = Xq;  // Xq dead after Q projection

  convw_k<<<256, 256, 0, stream>>>(Wq, Wqb);
  convw_k<<<256, 256, 0, stream>>>(Wk, Wkb);
  convw_k<<<256, 256, 0, stream>>>(Wv, Wvb);
  convw_k<<<256, 256, 0, stream>>>(Wo, Wob);
  tconv_k<<<dim3(128, 16, 16), dim3(32, 8), 0, stream>>>(feat0, feat1, Xq, Xkv);
  gemm_k<0><<<dim3(128, 8), 256, 0, stream>>>(Xq,  Wqb, bq, Qb,  nullptr, nullptr);
  gemm_k<3><<<dim3(128, 8), 256, 0, stream>>>(Xkv, Wkb, bk, Kb,  nullptr, nullptr);
  gemm_k<1><<<dim3(128, 8), 256, 0, stream>>>(Xkv, Wvb, bv, Vtb, nullptr, nullptr);
  flash_k<<<dim3(256), dim3(512), 0, stream>>>(Qb, Kb, Vtb, ctx);
  gemm_k<2><<<dim3(128, 8), 256, 0, stream>>>(ctx, Wob, bo, nullptr, out, feat0);
}